// Round 10
// baseline (127.651 us; speedup 1.0000x reference)
//
#include <hip/hip_runtime.h>
#include <hip/hip_bf16.h>

#define NB 16
#define CIN 256
#define CA 32
#define CH 128
#define NN 4096
#define MM 1024

typedef __attribute__((ext_vector_type(8))) short s16x8;
typedef __attribute__((ext_vector_type(4))) float f32x4;

static __device__ __forceinline__ unsigned short f2bf(float x) {
  __hip_bfloat16 h = __float2bfloat16(x);
  return __builtin_bit_cast(unsigned short, h);
}
static __device__ __forceinline__ float bf2f(unsigned short u) {
  unsigned int v = ((unsigned int)u) << 16;
  return __builtin_bit_cast(float, v);
}
// async global->LDS DMA, 16B per lane; lds dst is wave-uniform base + lane*16
static __device__ __forceinline__ void gload_lds16(const void* g, void* s) {
  __builtin_amdgcn_global_load_lds(
      (const __attribute__((address_space(1))) unsigned int*)g,
      (__attribute__((address_space(3))) unsigned int*)s, 16, 0, 0);
}

// Build wcat (192x256 bf16 = [w_theta; w_phi; w_g]) and wo2 (fragment-packed).
__global__ __launch_bounds__(256) void k_wcvt(const float* __restrict__ w_theta,
                                              const float* __restrict__ w_phi,
                                              const float* __restrict__ w_g,
                                              const float* __restrict__ w_o,
                                              unsigned short* __restrict__ wcat,
                                              unsigned short* __restrict__ wo2) {
  const int i = blockIdx.x * 256 + threadIdx.x;
  if (i < 8192) wcat[i] = f2bf(w_theta[i]);
  else if (i < 16384) wcat[i] = f2bf(w_phi[i - 8192]);
  else if (i < 49152) wcat[i] = f2bf(w_g[i - 16384]);
  else {
    const int w = i - 49152;
    const int c_out = w >> 7, k = w & 127;
    const int dst = (((c_out >> 4) * 16) + ((k >> 5) * 4) + ((k >> 3) & 3)) * 128 +
                    ((c_out & 15) << 3) + (k & 7);
    wo2[dst] = f2bf(w_o[w]);
  }
}

// Transpose-pack x (fp32, c-major) -> xp (bf16, MFMA-B-fragment-packed):
// element (c,n) at ((n>>4)*32 + (c>>3))*128 + (n&15)*8 + (c&7); batch stride 1M shorts.
__global__ __launch_bounds__(256) void k_prepack(const float* __restrict__ x,
                                                 unsigned short* __restrict__ xp) {
  __shared__ float lt[64][65];
  const int b = blockIdx.z;
  const int c0 = blockIdx.y * 64;
  const int n0 = blockIdx.x * 64;
  const int t = threadIdx.x;
  {
    const int cl = t >> 2, q = t & 3;
    const float* src = x + (size_t)b * CIN * NN + (size_t)(c0 + cl) * NN + n0 + q * 16;
#pragma unroll
    for (int k4 = 0; k4 < 4; ++k4) {
      const float4 v = *reinterpret_cast<const float4*>(src + k4 * 4);
      *reinterpret_cast<float4*>(&lt[cl][q * 16 + k4 * 4]) = v;
    }
  }
  __syncthreads();
  unsigned short* xpb = xp + (size_t)b * 1048576;
#pragma unroll
  for (int s = 0; s < 2; ++s) {
    const int i = t + s * 256;
    const int ntl = i >> 7, cgl = (i >> 4) & 7, nl = i & 15;
    unsigned int pk[4];
#pragma unroll
    for (int jp = 0; jp < 4; ++jp) {
      const unsigned short lo = f2bf(lt[cgl * 8 + 2 * jp][ntl * 16 + nl]);
      const unsigned short hi = f2bf(lt[cgl * 8 + 2 * jp + 1][ntl * 16 + nl]);
      pk[jp] = (unsigned)lo | ((unsigned)hi << 16);
    }
    *reinterpret_cast<uint4*>(
        &xpb[((size_t)((n0 >> 4) + ntl) * 32 + (c0 >> 3) + cgl) * 128 + nl * 8]) =
        make_uint4(pk[0], pk[1], pk[2], pk[3]);
  }
}

// MFMA projection from fragment-packed xp. Outputs:
//  theta (b,n,ca) row-major;
//  phi2 fragment-packed: (m,ca) -> (m>>4)*512 + (ca>>3)*128 + (m&15)*8 + (ca&7)
//  g2 fragment-packed:   (c,m)  -> ((m>>5)*8 + (c>>4))*512 + ((m>>3)&3)*128 + (c&15)*8 + (m&7)
__global__ __launch_bounds__(512) void k_proj(const unsigned short* __restrict__ xp,
                                              const unsigned short* __restrict__ wcat,
                                              unsigned short* __restrict__ theta,
                                              unsigned short* __restrict__ phi2,
                                              unsigned short* __restrict__ g2) {
  __shared__ unsigned short ol[192][136];
  const int b = blockIdx.y;
  const int t = blockIdx.x;
  const int tid = threadIdx.x;
  const int wv = tid >> 6;
  const int l = tid & 63;
  const int grp = l >> 4, col = l & 15;
  const unsigned short* xpb = xp + (size_t)b * 1048576;
  f32x4 acc[12];
#pragma unroll
  for (int r = 0; r < 12; ++r) acc[r] = f32x4{0.f, 0.f, 0.f, 0.f};
#pragma unroll 1
  for (int kc = 0; kc < 8; ++kc) {
    const s16x8 bfrag = *reinterpret_cast<const s16x8*>(
        xpb + ((size_t)(t * 8 + wv) * 32 + kc * 4 + grp) * 128 + col * 8);
    const int c0 = kc * 32 + grp * 8;
#pragma unroll
    for (int r = 0; r < 12; ++r) {
      const s16x8 af = *reinterpret_cast<const s16x8*>(
          wcat + (size_t)(r * 16 + col) * CIN + c0);
      acc[r] = __builtin_amdgcn_mfma_f32_16x16x32_bf16(af, bfrag, acc[r], 0, 0, 0);
    }
  }
#pragma unroll
  for (int r = 0; r < 12; ++r)
#pragma unroll
    for (int q = 0; q < 4; ++q)
      ol[r * 16 + grp * 4 + q][wv * 16 + col] = f2bf(acc[r][q]);
  __syncthreads();
  unsigned short* thb = theta + (size_t)b * NN * CA;
  for (int i = tid; i < 128 * 16; i += 512) {
    const int n = i >> 4, cp = (i & 15) << 1;
    const unsigned int v = (unsigned)ol[cp][n] | ((unsigned)ol[cp + 1][n] << 16);
    *reinterpret_cast<unsigned int*>(thb + (size_t)(t * 128 + n) * CA + cp) = v;
  }
  unsigned short* phb2 = phi2 + (size_t)b * MM * CA;
  for (int i = tid; i < 32 * 32; i += 512) {
    const int ca = i & 31, mx = i >> 5;
    const float v = fmaxf(
        fmaxf(bf2f(ol[32 + ca][2 * mx]), bf2f(ol[32 + ca][2 * mx + 1])),
        fmaxf(bf2f(ol[32 + ca][64 + 2 * mx]), bf2f(ol[32 + ca][64 + 2 * mx + 1])));
    const int m = t * 32 + mx;
    phb2[(m >> 4) * 512 + (ca >> 3) * 128 + (m & 15) * 8 + (ca & 7)] = f2bf(v);
  }
  unsigned short* gb2 = g2 + (size_t)b * CH * MM;
  for (int i = tid; i < 128 * 32; i += 512) {
    const int mx = i & 31, c = i >> 5;
    const float v = fmaxf(
        fmaxf(bf2f(ol[64 + c][2 * mx]), bf2f(ol[64 + c][2 * mx + 1])),
        fmaxf(bf2f(ol[64 + c][64 + 2 * mx]), bf2f(ol[64 + c][64 + 2 * mx + 1])));
    gb2[(size_t)(t * 8 + (c >> 4)) * 512 + ((mx >> 3) & 3) * 128 + (c & 15) * 8 +
        (mx & 7)] = f2bf(v);
  }
}

// Flash attention v3.1: 4 waves x 32 n-cols; LDS-staged K/V double-buffered via
// global_load_lds; single-nt pl buffer reused sequentially -> 49KB -> 3 blocks/CU.
__global__ __launch_bounds__(256, 3) void k_attn_out(
    const unsigned short* __restrict__ theta, const unsigned short* __restrict__ phi2,
    const unsigned short* __restrict__ g2, const unsigned short* __restrict__ wo2,
    const float* __restrict__ x, const float* __restrict__ gammap,
    float* __restrict__ out) {
  __shared__ __align__(16) unsigned short kv[2][10240];   // [buf][K 2048 | V 8192]
  __shared__ __align__(16) unsigned short pl[4][16][72];  // per-wave, reused per nt
  const int b = blockIdx.y;
  const int tid = threadIdx.x;
  const int wv = tid >> 6;
  const int l = tid & 63;
  const int grp = l >> 4, col = l & 15;
  const int n0 = blockIdx.x * 128 + wv * 32;
  const unsigned short* thb = theta + (size_t)b * NN * CA;
  const unsigned short* ph2b = phi2 + (size_t)b * MM * CA;
  const unsigned short* gb2 = g2 + (size_t)b * CH * MM;
  const s16x8 qf0 = *reinterpret_cast<const s16x8*>(thb + (size_t)(n0 + col) * CA + grp * 8);
  const s16x8 qf1 = *reinterpret_cast<const s16x8*>(thb + (size_t)(n0 + 16 + col) * CA + grp * 8);

  auto STAGE = [&](int buf, int tile) {
    const int mc = tile * 64;
    const unsigned short* ksrc = ph2b + (mc >> 4) * 512;
    const unsigned short* vsrc = gb2 + (size_t)(mc >> 5) * 4096;
#pragma unroll
    for (int q = 0; q < 5; ++q) {
      const int i = wv * 5 + q;
      const unsigned short* src = (i < 4) ? (ksrc + i * 512) : (vsrc + (i - 4) * 512);
      gload_lds16(src + (size_t)l * 8, &kv[buf][i * 512]);
    }
  };

  f32x4 oa0[8], oa1[8];
#pragma unroll
  for (int t = 0; t < 8; ++t) {
    oa0[t] = f32x4{0.f, 0.f, 0.f, 0.f};
    oa1[t] = f32x4{0.f, 0.f, 0.f, 0.f};
  }
  float m0 = -INFINITY, l0 = 0.f, m1 = -INFINITY, l1 = 0.f;
  const f32x4 z4 = {0.f, 0.f, 0.f, 0.f};

  STAGE(0, 0);
  __syncthreads();
#pragma unroll 1
  for (int it = 0; it < 16; ++it) {
    const int cur = it & 1;
    if (it < 15) STAGE(cur ^ 1, it + 1);  // fire-and-forget DMA for next tile
    const unsigned short* kb = &kv[cur][0];
    const unsigned short* vb = &kv[cur][2048];
    const int fo = grp * 128 + col * 8;
    const s16x8 kf0 = *reinterpret_cast<const s16x8*>(kb + 0 * 512 + fo);
    const s16x8 kf1 = *reinterpret_cast<const s16x8*>(kb + 1 * 512 + fo);
    const s16x8 kf2 = *reinterpret_cast<const s16x8*>(kb + 2 * 512 + fo);
    const s16x8 kf3 = *reinterpret_cast<const s16x8*>(kb + 3 * 512 + fo);
    f32x4 s00 = __builtin_amdgcn_mfma_f32_16x16x32_bf16(kf0, qf0, z4, 0, 0, 0);
    f32x4 s01 = __builtin_amdgcn_mfma_f32_16x16x32_bf16(kf1, qf0, z4, 0, 0, 0);
    f32x4 s02 = __builtin_amdgcn_mfma_f32_16x16x32_bf16(kf2, qf0, z4, 0, 0, 0);
    f32x4 s03 = __builtin_amdgcn_mfma_f32_16x16x32_bf16(kf3, qf0, z4, 0, 0, 0);
    f32x4 s10 = __builtin_amdgcn_mfma_f32_16x16x32_bf16(kf0, qf1, z4, 0, 0, 0);
    f32x4 s11 = __builtin_amdgcn_mfma_f32_16x16x32_bf16(kf1, qf1, z4, 0, 0, 0);
    f32x4 s12 = __builtin_amdgcn_mfma_f32_16x16x32_bf16(kf2, qf1, z4, 0, 0, 0);
    f32x4 s13 = __builtin_amdgcn_mfma_f32_16x16x32_bf16(kf3, qf1, z4, 0, 0, 0);
    float cm0 = -INFINITY, cm1 = -INFINITY;
#pragma unroll
    for (int r = 0; r < 4; ++r) {
      cm0 = fmaxf(cm0, fmaxf(fmaxf(s00[r], s01[r]), fmaxf(s02[r], s03[r])));
      cm1 = fmaxf(cm1, fmaxf(fmaxf(s10[r], s11[r]), fmaxf(s12[r], s13[r])));
    }
    cm0 = fmaxf(cm0, __shfl_xor(cm0, 16));
    cm0 = fmaxf(cm0, __shfl_xor(cm0, 32));
    cm1 = fmaxf(cm1, __shfl_xor(cm1, 16));
    cm1 = fmaxf(cm1, __shfl_xor(cm1, 32));
    if (!__all(cm0 <= m0 + 8.f && cm1 <= m1 + 8.f)) {  // defer-max (T13)
      const float mn0 = fmaxf(m0, cm0), mn1 = fmaxf(m1, cm1);
      const float sc0 = __expf(m0 - mn0), sc1 = __expf(m1 - mn1);
      l0 *= sc0;
      l1 *= sc1;
#pragma unroll
      for (int t = 0; t < 8; ++t) {
#pragma unroll
        for (int r = 0; r < 4; ++r) {
          oa0[t][r] *= sc0;
          oa1[t][r] *= sc1;
        }
      }
      m0 = mn0;
      m1 = mn1;
    }
    s16x8 pfA0, pfB0, pfA1, pfB1;
    {  // nt0 softmax -> pl -> pf0 fragments
      float p0[4], p1[4], p2[4], p3[4];
      float cs = 0.f;
#pragma unroll
      for (int r = 0; r < 4; ++r) {
        p0[r] = __expf(s00[r] - m0);
        p1[r] = __expf(s01[r] - m0);
        p2[r] = __expf(s02[r] - m0);
        p3[r] = __expf(s03[r] - m0);
        cs += (p0[r] + p1[r]) + (p2[r] + p3[r]);
      }
      cs += __shfl_xor(cs, 16);
      cs += __shfl_xor(cs, 32);
      l0 += cs;
      *reinterpret_cast<uint2*>(&pl[wv][col][grp * 4]) =
          make_uint2((unsigned)f2bf(p0[0]) | ((unsigned)f2bf(p0[1]) << 16),
                     (unsigned)f2bf(p0[2]) | ((unsigned)f2bf(p0[3]) << 16));
      *reinterpret_cast<uint2*>(&pl[wv][col][16 + grp * 4]) =
          make_uint2((unsigned)f2bf(p1[0]) | ((unsigned)f2bf(p1[1]) << 16),
                     (unsigned)f2bf(p1[2]) | ((unsigned)f2bf(p1[3]) << 16));
      *reinterpret_cast<uint2*>(&pl[wv][col][32 + grp * 4]) =
          make_uint2((unsigned)f2bf(p2[0]) | ((unsigned)f2bf(p2[1]) << 16),
                     (unsigned)f2bf(p2[2]) | ((unsigned)f2bf(p2[3]) << 16));
      *reinterpret_cast<uint2*>(&pl[wv][col][48 + grp * 4]) =
          make_uint2((unsigned)f2bf(p3[0]) | ((unsigned)f2bf(p3[1]) << 16),
                     (unsigned)f2bf(p3[2]) | ((unsigned)f2bf(p3[3]) << 16));
      pfA0 = *reinterpret_cast<const s16x8*>(&pl[wv][col][grp * 8]);
      pfB0 = *reinterpret_cast<const s16x8*>(&pl[wv][col][32 + grp * 8]);
    }
    {  // nt1 softmax -> pl (reuse) -> pf1 fragments
      float p0[4], p1[4], p2[4], p3[4];
      float cs = 0.f;
#pragma unroll
      for (int r = 0; r < 4; ++r) {
        p0[r] = __expf(s10[r] - m1);
        p1[r] = __expf(s11[r] - m1);
        p2[r] = __expf(s12[r] - m1);
        p3[r] = __expf(s13[r] - m1);
        cs += (p0[r] + p1[r]) + (p2[r] + p3[r]);
      }
      cs += __shfl_xor(cs, 16);
      cs += __shfl_xor(cs, 32);
      l1 += cs;
      *reinterpret_cast<uint2*>(&pl[wv][col][grp * 4]) =
          make_uint2((unsigned)f2bf(p0[0]) | ((unsigned)f2bf(p0[1]) << 16),
                     (unsigned)f2bf(p0[2]) | ((unsigned)f2bf(p0[3]) << 16));
      *reinterpret_cast<uint2*>(&pl[wv][col][16 + grp * 4]) =
          make_uint2((unsigned)f2bf(p1[0]) | ((unsigned)f2bf(p1[1]) << 16),
                     (unsigned)f2bf(p1[2]) | ((unsigned)f2bf(p1[3]) << 16));
      *reinterpret_cast<uint2*>(&pl[wv][col][32 + grp * 4]) =
          make_uint2((unsigned)f2bf(p2[0]) | ((unsigned)f2bf(p2[1]) << 16),
                     (unsigned)f2bf(p2[2]) | ((unsigned)f2bf(p2[3]) << 16));
      *reinterpret_cast<uint2*>(&pl[wv][col][48 + grp * 4]) =
          make_uint2((unsigned)f2bf(p3[0]) | ((unsigned)f2bf(p3[1]) << 16),
                     (unsigned)f2bf(p3[2]) | ((unsigned)f2bf(p3[3]) << 16));
      pfA1 = *reinterpret_cast<const s16x8*>(&pl[wv][col][grp * 8]);
      pfB1 = *reinterpret_cast<const s16x8*>(&pl[wv][col][32 + grp * 8]);
    }
#pragma unroll
    for (int t = 0; t < 8; ++t) {
      const s16x8 vfA = *reinterpret_cast<const s16x8*>(vb + t * 512 + fo);
      const s16x8 vfB = *reinterpret_cast<const s16x8*>(vb + 4096 + t * 512 + fo);
      oa0[t] = __builtin_amdgcn_mfma_f32_16x16x32_bf16(vfA, pfA0, oa0[t], 0, 0, 0);
      oa0[t] = __builtin_amdgcn_mfma_f32_16x16x32_bf16(vfB, pfB0, oa0[t], 0, 0, 0);
      oa1[t] = __builtin_amdgcn_mfma_f32_16x16x32_bf16(vfA, pfA1, oa1[t], 0, 0, 0);
      oa1[t] = __builtin_amdgcn_mfma_f32_16x16x32_bf16(vfB, pfB1, oa1[t], 0, 0, 0);
    }
    __syncthreads();
  }
  // ---- epilogue: normalize own O, stage in LDS (reuse kv), project ----
  unsigned short* obw = &kv[0][0] + (size_t)wv * (32 * 136);
  const float ri0 = 1.f / l0, ri1 = 1.f / l1;
#pragma unroll
  for (int t = 0; t < 8; ++t) {
    *reinterpret_cast<uint2*>(obw + col * 136 + t * 16 + grp * 4) =
        make_uint2((unsigned)f2bf(oa0[t][0] * ri0) | ((unsigned)f2bf(oa0[t][1] * ri0) << 16),
                   (unsigned)f2bf(oa0[t][2] * ri0) | ((unsigned)f2bf(oa0[t][3] * ri0) << 16));
    *reinterpret_cast<uint2*>(obw + (16 + col) * 136 + t * 16 + grp * 4) =
        make_uint2((unsigned)f2bf(oa1[t][0] * ri1) | ((unsigned)f2bf(oa1[t][1] * ri1) << 16),
                   (unsigned)f2bf(oa1[t][2] * ri1) | ((unsigned)f2bf(oa1[t][3] * ri1) << 16));
  }
  s16x8 of0[4], of1[4];
#pragma unroll
  for (int ks = 0; ks < 4; ++ks) {
    of0[ks] = *reinterpret_cast<const s16x8*>(obw + col * 136 + ks * 32 + grp * 8);
    of1[ks] = *reinterpret_cast<const s16x8*>(obw + (16 + col) * 136 + ks * 32 + grp * 8);
  }
  const float gamma = gammap[0];
  const float* xb2 = x + (size_t)b * CIN * NN;
  float* outb = out + (size_t)b * CIN * NN;
#pragma unroll 1
  for (int t2 = 0; t2 < 16; ++t2) {
    f32x4 a20 = {0.f, 0.f, 0.f, 0.f};
    f32x4 a21 = {0.f, 0.f, 0.f, 0.f};
#pragma unroll
    for (int ks = 0; ks < 4; ++ks) {
      const s16x8 wf = *reinterpret_cast<const s16x8*>(
          wo2 + (size_t)(t2 * 16 + ks * 4 + grp) * 128 + col * 8);
      a20 = __builtin_amdgcn_mfma_f32_16x16x32_bf16(wf, of0[ks], a20, 0, 0, 0);
      a21 = __builtin_amdgcn_mfma_f32_16x16x32_bf16(wf, of1[ks], a21, 0, 0, 0);
    }
#pragma unroll
    for (int r = 0; r < 4; ++r) {
      const size_t idx = (size_t)(t2 * 16 + grp * 4 + r) * NN + n0 + col;
      outb[idx] = fmaf(gamma, a20[r], xb2[idx]);
      outb[idx + 16] = fmaf(gamma, a21[r], xb2[idx + 16]);
    }
  }
}

extern "C" void kernel_launch(void* const* d_in, const int* in_sizes, int n_in,
                              void* d_out, int out_size, void* d_ws, size_t ws_size,
                              hipStream_t stream) {
  const float* x = (const float*)d_in[0];
  const float* w_theta = (const float*)d_in[1];
  const float* w_phi = (const float*)d_in[2];
  const float* w_g = (const float*)d_in[3];
  const float* w_o = (const float*)d_in[4];
  const float* gamma = (const float*)d_in[5];
  float* out = (float*)d_out;
  char* ws = (char*)d_ws;
  unsigned short* theta = (unsigned short*)(ws + 0);
  unsigned short* phi2 = (unsigned short*)(ws + 4194304);
  unsigned short* g2 = (unsigned short*)(ws + 5242880);
  unsigned short* wo2 = (unsigned short*)(ws + 9437184);
  unsigned short* wcat = (unsigned short*)(ws + 9502720);
  // xp (32MB bf16) lives in d_out: fully written by k_prepack, fully consumed
  // by k_proj BEFORE k_attn_out overwrites out (stream-ordered).
  unsigned short* xp = (unsigned short*)d_out;

  k_wcvt<<<dim3(320), 256, 0, stream>>>(w_theta, w_phi, w_g, w_o, wcat, wo2);
  k_prepack<<<dim3(NN / 64, CIN / 64, NB), 256, 0, stream>>>(x, xp);
  k_proj<<<dim3(NN / 128, NB), 512, 0, stream>>>(xp, wcat, theta, phi2, g2);
  k_attn_out<<<dim3(NN / 128, NB), 256, 0, stream>>>(theta, phi2, g2, wo2, x, gamma, out);
}

// Round 11
// 113.822 us; speedup vs baseline: 1.1215x; 1.1215x over previous
//
#include <hip/hip_runtime.h>
#include <hip/hip_bf16.h>

#define NB 16
#define CIN 256
#define CA 32
#define CH 128
#define NN 4096
#define MM 1024

typedef __attribute__((ext_vector_type(8))) short s16x8;
typedef __attribute__((ext_vector_type(4))) float f32x4;

static __device__ __forceinline__ unsigned short f2bf(float x) {
  __hip_bfloat16 h = __float2bfloat16(x);
  return __builtin_bit_cast(unsigned short, h);
}
static __device__ __forceinline__ float bf2f(unsigned short u) {
  unsigned int v = ((unsigned int)u) << 16;
  return __builtin_bit_cast(float, v);
}
// async global->LDS DMA, 16B per lane; lds dst is wave-uniform base + lane*16
static __device__ __forceinline__ void gload_lds16(const void* g, void* s) {
  __builtin_amdgcn_global_load_lds(
      (const __attribute__((address_space(1))) unsigned int*)g,
      (__attribute__((address_space(3))) unsigned int*)s, 16, 0, 0);
}

// Build wcat (192x256 bf16 = [w_theta; w_phi; w_g]) and wo2 (fragment-packed).
__global__ __launch_bounds__(256) void k_wcvt(const float* __restrict__ w_theta,
                                              const float* __restrict__ w_phi,
                                              const float* __restrict__ w_g,
                                              const float* __restrict__ w_o,
                                              unsigned short* __restrict__ wcat,
                                              unsigned short* __restrict__ wo2) {
  const int i = blockIdx.x * 256 + threadIdx.x;
  if (i < 8192) wcat[i] = f2bf(w_theta[i]);
  else if (i < 16384) wcat[i] = f2bf(w_phi[i - 8192]);
  else if (i < 49152) wcat[i] = f2bf(w_g[i - 16384]);
  else {
    const int w = i - 49152;
    const int c_out = w >> 7, k = w & 127;
    const int dst = (((c_out >> 4) * 16) + ((k >> 5) * 4) + ((k >> 3) & 3)) * 128 +
                    ((c_out & 15) << 3) + (k & 7);
    wo2[dst] = f2bf(w_o[w]);
  }
}

// MFMA projection with fused in-LDS transpose of x (no extra global traffic).
// Per 32-c chunk: coalesced float4 reads -> bf16 -> LDS [c(32)][n(128)+pad];
// B-fragment built from 8 ds_read_u16. Outputs:
//  theta (b,n,ca) row-major;
//  phi2 fragment-packed: (m,ca) -> (m>>4)*512 + (ca>>3)*128 + (m&15)*8 + (ca&7)
//  g2 fragment-packed:   (c,m)  -> ((m>>5)*8 + (c>>4))*512 + ((m>>3)&3)*128 + (c&15)*8 + (m&7)
__global__ __launch_bounds__(512) void k_proj(const float* __restrict__ x,
                                              const unsigned short* __restrict__ wcat,
                                              unsigned short* __restrict__ theta,
                                              unsigned short* __restrict__ phi2,
                                              unsigned short* __restrict__ g2) {
  __shared__ unsigned short xl[32][140];   // [c][n] bf16 chunk, pad->140
  __shared__ unsigned short ol[192][136];  // conv out [row][n_local]
  const int b = blockIdx.y;
  const int t = blockIdx.x;
  const int tid = threadIdx.x;
  const int wv = tid >> 6;
  const int l = tid & 63;
  const int grp = l >> 4, col = l & 15;
  const float* xb = x + (size_t)b * CIN * NN;
  f32x4 acc[12];
#pragma unroll
  for (int r = 0; r < 12; ++r) acc[r] = f32x4{0.f, 0.f, 0.f, 0.f};
#pragma unroll 1
  for (int kc = 0; kc < 8; ++kc) {
    // stage chunk: x[kc*32 .. +31][t*128 .. +127] -> xl (bf16, transposed-friendly)
#pragma unroll
    for (int s = 0; s < 2; ++s) {
      const int i = tid + s * 512;
      const int cl = i >> 5, nq = i & 31;  // cl 0..31, nq 0..31 (4 floats each)
      const float4 v = *reinterpret_cast<const float4*>(
          xb + (size_t)(kc * 32 + cl) * NN + t * 128 + nq * 4);
      const unsigned int lo = (unsigned)f2bf(v.x) | ((unsigned)f2bf(v.y) << 16);
      const unsigned int hi = (unsigned)f2bf(v.z) | ((unsigned)f2bf(v.w) << 16);
      *reinterpret_cast<uint2*>(&xl[cl][nq * 4]) = make_uint2(lo, hi);
    }
    __syncthreads();
    // B fragment: lane holds col n = wv*16+col, k(c) = kc*32 + grp*8 .. +7
    s16x8 bfrag;
#pragma unroll
    for (int j = 0; j < 8; ++j)
      bfrag[j] = (short)xl[grp * 8 + j][wv * 16 + col];
    const int c0 = kc * 32 + grp * 8;
#pragma unroll
    for (int r = 0; r < 12; ++r) {
      const s16x8 af = *reinterpret_cast<const s16x8*>(
          wcat + (size_t)(r * 16 + col) * CIN + c0);
      acc[r] = __builtin_amdgcn_mfma_f32_16x16x32_bf16(af, bfrag, acc[r], 0, 0, 0);
    }
    __syncthreads();  // protect xl before next chunk's writes
  }
#pragma unroll
  for (int r = 0; r < 12; ++r)
#pragma unroll
    for (int q = 0; q < 4; ++q)
      ol[r * 16 + grp * 4 + q][wv * 16 + col] = f2bf(acc[r][q]);
  __syncthreads();
  unsigned short* thb = theta + (size_t)b * NN * CA;
  for (int i = tid; i < 128 * 16; i += 512) {
    const int n = i >> 4, cp = (i & 15) << 1;
    const unsigned int v = (unsigned)ol[cp][n] | ((unsigned)ol[cp + 1][n] << 16);
    *reinterpret_cast<unsigned int*>(thb + (size_t)(t * 128 + n) * CA + cp) = v;
  }
  unsigned short* phb2 = phi2 + (size_t)b * MM * CA;
  for (int i = tid; i < 32 * 32; i += 512) {
    const int ca = i & 31, mx = i >> 5;
    const float v = fmaxf(
        fmaxf(bf2f(ol[32 + ca][2 * mx]), bf2f(ol[32 + ca][2 * mx + 1])),
        fmaxf(bf2f(ol[32 + ca][64 + 2 * mx]), bf2f(ol[32 + ca][64 + 2 * mx + 1])));
    const int m = t * 32 + mx;
    phb2[(m >> 4) * 512 + (ca >> 3) * 128 + (m & 15) * 8 + (ca & 7)] = f2bf(v);
  }
  unsigned short* gb2 = g2 + (size_t)b * CH * MM;
  for (int i = tid; i < 128 * 32; i += 512) {
    const int mx = i & 31, c = i >> 5;
    const float v = fmaxf(
        fmaxf(bf2f(ol[64 + c][2 * mx]), bf2f(ol[64 + c][2 * mx + 1])),
        fmaxf(bf2f(ol[64 + c][64 + 2 * mx]), bf2f(ol[64 + c][64 + 2 * mx + 1])));
    gb2[(size_t)(t * 8 + (c >> 4)) * 512 + ((mx >> 3) & 3) * 128 + (c & 15) * 8 +
        (mx & 7)] = f2bf(v);
  }
}

// Flash attention v3.1: 4 waves x 32 n-cols; LDS-staged K/V double-buffered via
// global_load_lds; single-nt pl buffer reused sequentially.
__global__ __launch_bounds__(256, 3) void k_attn_out(
    const unsigned short* __restrict__ theta, const unsigned short* __restrict__ phi2,
    const unsigned short* __restrict__ g2, const unsigned short* __restrict__ wo2,
    const float* __restrict__ x, const float* __restrict__ gammap,
    float* __restrict__ out) {
  __shared__ __align__(16) unsigned short kv[2][10240];   // [buf][K 2048 | V 8192]
  __shared__ __align__(16) unsigned short pl[4][16][72];  // per-wave, reused per nt
  const int b = blockIdx.y;
  const int tid = threadIdx.x;
  const int wv = tid >> 6;
  const int l = tid & 63;
  const int grp = l >> 4, col = l & 15;
  const int n0 = blockIdx.x * 128 + wv * 32;
  const unsigned short* thb = theta + (size_t)b * NN * CA;
  const unsigned short* ph2b = phi2 + (size_t)b * MM * CA;
  const unsigned short* gb2 = g2 + (size_t)b * CH * MM;
  const s16x8 qf0 = *reinterpret_cast<const s16x8*>(thb + (size_t)(n0 + col) * CA + grp * 8);
  const s16x8 qf1 = *reinterpret_cast<const s16x8*>(thb + (size_t)(n0 + 16 + col) * CA + grp * 8);

  auto STAGE = [&](int buf, int tile) {
    const int mc = tile * 64;
    const unsigned short* ksrc = ph2b + (mc >> 4) * 512;
    const unsigned short* vsrc = gb2 + (size_t)(mc >> 5) * 4096;
#pragma unroll
    for (int q = 0; q < 5; ++q) {
      const int i = wv * 5 + q;
      const unsigned short* src = (i < 4) ? (ksrc + i * 512) : (vsrc + (i - 4) * 512);
      gload_lds16(src + (size_t)l * 8, &kv[buf][i * 512]);
    }
  };

  f32x4 oa0[8], oa1[8];
#pragma unroll
  for (int t = 0; t < 8; ++t) {
    oa0[t] = f32x4{0.f, 0.f, 0.f, 0.f};
    oa1[t] = f32x4{0.f, 0.f, 0.f, 0.f};
  }
  float m0 = -INFINITY, l0 = 0.f, m1 = -INFINITY, l1 = 0.f;
  const f32x4 z4 = {0.f, 0.f, 0.f, 0.f};

  STAGE(0, 0);
  __syncthreads();
#pragma unroll 1
  for (int it = 0; it < 16; ++it) {
    const int cur = it & 1;
    if (it < 15) STAGE(cur ^ 1, it + 1);  // fire-and-forget DMA for next tile
    const unsigned short* kb = &kv[cur][0];
    const unsigned short* vb = &kv[cur][2048];
    const int fo = grp * 128 + col * 8;
    const s16x8 kf0 = *reinterpret_cast<const s16x8*>(kb + 0 * 512 + fo);
    const s16x8 kf1 = *reinterpret_cast<const s16x8*>(kb + 1 * 512 + fo);
    const s16x8 kf2 = *reinterpret_cast<const s16x8*>(kb + 2 * 512 + fo);
    const s16x8 kf3 = *reinterpret_cast<const s16x8*>(kb + 3 * 512 + fo);
    f32x4 s00 = __builtin_amdgcn_mfma_f32_16x16x32_bf16(kf0, qf0, z4, 0, 0, 0);
    f32x4 s01 = __builtin_amdgcn_mfma_f32_16x16x32_bf16(kf1, qf0, z4, 0, 0, 0);
    f32x4 s02 = __builtin_amdgcn_mfma_f32_16x16x32_bf16(kf2, qf0, z4, 0, 0, 0);
    f32x4 s03 = __builtin_amdgcn_mfma_f32_16x16x32_bf16(kf3, qf0, z4, 0, 0, 0);
    f32x4 s10 = __builtin_amdgcn_mfma_f32_16x16x32_bf16(kf0, qf1, z4, 0, 0, 0);
    f32x4 s11 = __builtin_amdgcn_mfma_f32_16x16x32_bf16(kf1, qf1, z4, 0, 0, 0);
    f32x4 s12 = __builtin_amdgcn_mfma_f32_16x16x32_bf16(kf2, qf1, z4, 0, 0, 0);
    f32x4 s13 = __builtin_amdgcn_mfma_f32_16x16x32_bf16(kf3, qf1, z4, 0, 0, 0);
    float cm0 = -INFINITY, cm1 = -INFINITY;
#pragma unroll
    for (int r = 0; r < 4; ++r) {
      cm0 = fmaxf(cm0, fmaxf(fmaxf(s00[r], s01[r]), fmaxf(s02[r], s03[r])));
      cm1 = fmaxf(cm1, fmaxf(fmaxf(s10[r], s11[r]), fmaxf(s12[r], s13[r])));
    }
    cm0 = fmaxf(cm0, __shfl_xor(cm0, 16));
    cm0 = fmaxf(cm0, __shfl_xor(cm0, 32));
    cm1 = fmaxf(cm1, __shfl_xor(cm1, 16));
    cm1 = fmaxf(cm1, __shfl_xor(cm1, 32));
    if (!__all(cm0 <= m0 + 8.f && cm1 <= m1 + 8.f)) {  // defer-max (T13)
      const float mn0 = fmaxf(m0, cm0), mn1 = fmaxf(m1, cm1);
      const float sc0 = __expf(m0 - mn0), sc1 = __expf(m1 - mn1);
      l0 *= sc0;
      l1 *= sc1;
#pragma unroll
      for (int t = 0; t < 8; ++t) {
#pragma unroll
        for (int r = 0; r < 4; ++r) {
          oa0[t][r] *= sc0;
          oa1[t][r] *= sc1;
        }
      }
      m0 = mn0;
      m1 = mn1;
    }
    s16x8 pfA0, pfB0, pfA1, pfB1;
    {  // nt0 softmax -> pl -> pf0 fragments
      float p0[4], p1[4], p2[4], p3[4];
      float cs = 0.f;
#pragma unroll
      for (int r = 0; r < 4; ++r) {
        p0[r] = __expf(s00[r] - m0);
        p1[r] = __expf(s01[r] - m0);
        p2[r] = __expf(s02[r] - m0);
        p3[r] = __expf(s03[r] - m0);
        cs += (p0[r] + p1[r]) + (p2[r] + p3[r]);
      }
      cs += __shfl_xor(cs, 16);
      cs += __shfl_xor(cs, 32);
      l0 += cs;
      *reinterpret_cast<uint2*>(&pl[wv][col][grp * 4]) =
          make_uint2((unsigned)f2bf(p0[0]) | ((unsigned)f2bf(p0[1]) << 16),
                     (unsigned)f2bf(p0[2]) | ((unsigned)f2bf(p0[3]) << 16));
      *reinterpret_cast<uint2*>(&pl[wv][col][16 + grp * 4]) =
          make_uint2((unsigned)f2bf(p1[0]) | ((unsigned)f2bf(p1[1]) << 16),
                     (unsigned)f2bf(p1[2]) | ((unsigned)f2bf(p1[3]) << 16));
      *reinterpret_cast<uint2*>(&pl[wv][col][32 + grp * 4]) =
          make_uint2((unsigned)f2bf(p2[0]) | ((unsigned)f2bf(p2[1]) << 16),
                     (unsigned)f2bf(p2[2]) | ((unsigned)f2bf(p2[3]) << 16));
      *reinterpret_cast<uint2*>(&pl[wv][col][48 + grp * 4]) =
          make_uint2((unsigned)f2bf(p3[0]) | ((unsigned)f2bf(p3[1]) << 16),
                     (unsigned)f2bf(p3[2]) | ((unsigned)f2bf(p3[3]) << 16));
      pfA0 = *reinterpret_cast<const s16x8*>(&pl[wv][col][grp * 8]);
      pfB0 = *reinterpret_cast<const s16x8*>(&pl[wv][col][32 + grp * 8]);
    }
    {  // nt1 softmax -> pl (reuse) -> pf1 fragments
      float p0[4], p1[4], p2[4], p3[4];
      float cs = 0.f;
#pragma unroll
      for (int r = 0; r < 4; ++r) {
        p0[r] = __expf(s10[r] - m1);
        p1[r] = __expf(s11[r] - m1);
        p2[r] = __expf(s12[r] - m1);
        p3[r] = __expf(s13[r] - m1);
        cs += (p0[r] + p1[r]) + (p2[r] + p3[r]);
      }
      cs += __shfl_xor(cs, 16);
      cs += __shfl_xor(cs, 32);
      l1 += cs;
      *reinterpret_cast<uint2*>(&pl[wv][col][grp * 4]) =
          make_uint2((unsigned)f2bf(p0[0]) | ((unsigned)f2bf(p0[1]) << 16),
                     (unsigned)f2bf(p0[2]) | ((unsigned)f2bf(p0[3]) << 16));
      *reinterpret_cast<uint2*>(&pl[wv][col][16 + grp * 4]) =
          make_uint2((unsigned)f2bf(p1[0]) | ((unsigned)f2bf(p1[1]) << 16),
                     (unsigned)f2bf(p1[2]) | ((unsigned)f2bf(p1[3]) << 16));
      *reinterpret_cast<uint2*>(&pl[wv][col][32 + grp * 4]) =
          make_uint2((unsigned)f2bf(p2[0]) | ((unsigned)f2bf(p2[1]) << 16),
                     (unsigned)f2bf(p2[2]) | ((unsigned)f2bf(p2[3]) << 16));
      *reinterpret_cast<uint2*>(&pl[wv][col][48 + grp * 4]) =
          make_uint2((unsigned)f2bf(p3[0]) | ((unsigned)f2bf(p3[1]) << 16),
                     (unsigned)f2bf(p3[2]) | ((unsigned)f2bf(p3[3]) << 16));
      pfA1 = *reinterpret_cast<const s16x8*>(&pl[wv][col][grp * 8]);
      pfB1 = *reinterpret_cast<const s16x8*>(&pl[wv][col][32 + grp * 8]);
    }
#pragma unroll
    for (int t = 0; t < 8; ++t) {
      const s16x8 vfA = *reinterpret_cast<const s16x8*>(vb + t * 512 + fo);
      const s16x8 vfB = *reinterpret_cast<const s16x8*>(vb + 4096 + t * 512 + fo);
      oa0[t] = __builtin_amdgcn_mfma_f32_16x16x32_bf16(vfA, pfA0, oa0[t], 0, 0, 0);
      oa0[t] = __builtin_amdgcn_mfma_f32_16x16x32_bf16(vfB, pfB0, oa0[t], 0, 0, 0);
      oa1[t] = __builtin_amdgcn_mfma_f32_16x16x32_bf16(vfA, pfA1, oa1[t], 0, 0, 0);
      oa1[t] = __builtin_amdgcn_mfma_f32_16x16x32_bf16(vfB, pfB1, oa1[t], 0, 0, 0);
    }
    __syncthreads();
  }
  // ---- epilogue: normalize own O, stage in LDS (reuse kv), project ----
  unsigned short* obw = &kv[0][0] + (size_t)wv * (32 * 136);
  const float ri0 = 1.f / l0, ri1 = 1.f / l1;
#pragma unroll
  for (int t = 0; t < 8; ++t) {
    *reinterpret_cast<uint2*>(obw + col * 136 + t * 16 + grp * 4) =
        make_uint2((unsigned)f2bf(oa0[t][0] * ri0) | ((unsigned)f2bf(oa0[t][1] * ri0) << 16),
                   (unsigned)f2bf(oa0[t][2] * ri0) | ((unsigned)f2bf(oa0[t][3] * ri0) << 16));
    *reinterpret_cast<uint2*>(obw + (16 + col) * 136 + t * 16 + grp * 4) =
        make_uint2((unsigned)f2bf(oa1[t][0] * ri1) | ((unsigned)f2bf(oa1[t][1] * ri1) << 16),
                   (unsigned)f2bf(oa1[t][2] * ri1) | ((unsigned)f2bf(oa1[t][3] * ri1) << 16));
  }
  s16x8 of0[4], of1[4];
#pragma unroll
  for (int ks = 0; ks < 4; ++ks) {
    of0[ks] = *reinterpret_cast<const s16x8*>(obw + col * 136 + ks * 32 + grp * 8);
    of1[ks] = *reinterpret_cast<const s16x8*>(obw + (16 + col) * 136 + ks * 32 + grp * 8);
  }
  const float gamma = gammap[0];
  const float* xb2 = x + (size_t)b * CIN * NN;
  float* outb = out + (size_t)b * CIN * NN;
#pragma unroll 1
  for (int t2 = 0; t2 < 16; ++t2) {
    f32x4 a20 = {0.f, 0.f, 0.f, 0.f};
    f32x4 a21 = {0.f, 0.f, 0.f, 0.f};
#pragma unroll
    for (int ks = 0; ks < 4; ++ks) {
      const s16x8 wf = *reinterpret_cast<const s16x8*>(
          wo2 + (size_t)(t2 * 16 + ks * 4 + grp) * 128 + col * 8);
      a20 = __builtin_amdgcn_mfma_f32_16x16x32_bf16(wf, of0[ks], a20, 0, 0, 0);
      a21 = __builtin_amdgcn_mfma_f32_16x16x32_bf16(wf, of1[ks], a21, 0, 0, 0);
    }
#pragma unroll
    for (int r = 0; r < 4; ++r) {
      const size_t idx = (size_t)(t2 * 16 + grp * 4 + r) * NN + n0 + col;
      outb[idx] = fmaf(gamma, a20[r], xb2[idx]);
      outb[idx + 16] = fmaf(gamma, a21[r], xb2[idx + 16]);
    }
  }
}

extern "C" void kernel_launch(void* const* d_in, const int* in_sizes, int n_in,
                              void* d_out, int out_size, void* d_ws, size_t ws_size,
                              hipStream_t stream) {
  const float* x = (const float*)d_in[0];
  const float* w_theta = (const float*)d_in[1];
  const float* w_phi = (const float*)d_in[2];
  const float* w_g = (const float*)d_in[3];
  const float* w_o = (const float*)d_in[4];
  const float* gamma = (const float*)d_in[5];
  float* out = (float*)d_out;
  char* ws = (char*)d_ws;
  unsigned short* theta = (unsigned short*)(ws + 0);
  unsigned short* phi2 = (unsigned short*)(ws + 4194304);
  unsigned short* g2 = (unsigned short*)(ws + 5242880);
  unsigned short* wo2 = (unsigned short*)(ws + 9437184);
  unsigned short* wcat = (unsigned short*)(ws + 9502720);

  k_wcvt<<<dim3(320), 256, 0, stream>>>(w_theta, w_phi, w_g, w_o, wcat, wo2);
  k_proj<<<dim3(NN / 128, NB), 512, 0, stream>>>(x, wcat, theta, phi2, g2);
  k_attn_out<<<dim3(NN / 128, NB), 256, 0, stream>>>(theta, phi2, g2, wo2, x, gamma, out);
}

// Round 12
// 88.903 us; speedup vs baseline: 1.4358x; 1.2803x over previous
//
#include <hip/hip_runtime.h>
#include <hip/hip_bf16.h>

#define NB 16
#define CIN 256
#define CA 32
#define CH 128
#define NN 4096
#define MM 1024

typedef __attribute__((ext_vector_type(8))) short s16x8;
typedef __attribute__((ext_vector_type(4))) float f32x4;

static __device__ __forceinline__ unsigned short f2bf(float x) {
  __hip_bfloat16 h = __float2bfloat16(x);
  return __builtin_bit_cast(unsigned short, h);
}
static __device__ __forceinline__ float bf2f(unsigned short u) {
  unsigned int v = ((unsigned int)u) << 16;
  return __builtin_bit_cast(float, v);
}
// async global->LDS DMA, 16B per lane; lds dst is wave-uniform base + lane*16
static __device__ __forceinline__ void gload_lds16(const void* g, void* s) {
  __builtin_amdgcn_global_load_lds(
      (const __attribute__((address_space(1))) unsigned int*)g,
      (__attribute__((address_space(3))) unsigned int*)s, 16, 0, 0);
}

// Build wcat2 (A-fragment-packed [w_theta; w_phi; w_g]) and wo2 (fragment-packed).
// wcat2: element (row,c) -> ((row>>4)*8 + (c>>5))*512 + (((c>>3)&3)*16 + (row&15))*8 + (c&7)
__global__ __launch_bounds__(256) void k_wcvt(const float* __restrict__ w_theta,
                                              const float* __restrict__ w_phi,
                                              const float* __restrict__ w_g,
                                              const float* __restrict__ w_o,
                                              unsigned short* __restrict__ wcat2,
                                              unsigned short* __restrict__ wo2) {
  const int i = blockIdx.x * 256 + threadIdx.x;
  if (i < 49152) {
    const int row = i >> 8, c = i & 255;
    const float v = (row < 32) ? w_theta[i]
                  : (row < 64) ? w_phi[i - 8192]
                               : w_g[i - 16384];
    const int dst = ((row >> 4) * 8 + (c >> 5)) * 512 +
                    (((c >> 3) & 3) * 16 + (row & 15)) * 8 + (c & 7);
    wcat2[dst] = f2bf(v);
  } else {
    const int w = i - 49152;
    const int c_out = w >> 7, k = w & 127;
    const int dst = (((c_out >> 4) * 16) + ((k >> 5) * 4) + ((k >> 3) & 3)) * 128 +
                    ((c_out & 15) << 3) + (k & 7);
    wo2[dst] = f2bf(w_o[w]);
  }
}

// MFMA projection, fused in-LDS transpose of x, A-fragments contiguous from wcat2.
// Outputs: theta (b,n,ca) row-major;
//  phi2 fragment-packed: (m,ca) -> (m>>4)*512 + (ca>>3)*128 + (m&15)*8 + (ca&7)
//  g2 fragment-packed:   (c,m)  -> ((m>>5)*8 + (c>>4))*512 + ((m>>3)&3)*128 + (c&15)*8 + (m&7)
__global__ __launch_bounds__(512) void k_proj(const float* __restrict__ x,
                                              const unsigned short* __restrict__ wcat2,
                                              unsigned short* __restrict__ theta,
                                              unsigned short* __restrict__ phi2,
                                              unsigned short* __restrict__ g2) {
  __shared__ unsigned short xl[32][140];   // [c][n] bf16 chunk, pad->140
  __shared__ unsigned short ol[192][136];  // conv out [row][n_local]
  const int b = blockIdx.y;
  const int t = blockIdx.x;
  const int tid = threadIdx.x;
  const int wv = tid >> 6;
  const int l = tid & 63;
  const int grp = l >> 4, col = l & 15;
  const float* xb = x + (size_t)b * CIN * NN;
  f32x4 acc[12];
#pragma unroll
  for (int r = 0; r < 12; ++r) acc[r] = f32x4{0.f, 0.f, 0.f, 0.f};
#pragma unroll 1
  for (int kc = 0; kc < 8; ++kc) {
    // stage chunk: x[kc*32 .. +31][t*128 .. +127] -> xl (bf16)
#pragma unroll
    for (int s = 0; s < 2; ++s) {
      const int i = tid + s * 512;
      const int cl = i >> 5, nq = i & 31;
      const float4 v = *reinterpret_cast<const float4*>(
          xb + (size_t)(kc * 32 + cl) * NN + t * 128 + nq * 4);
      const unsigned int lo = (unsigned)f2bf(v.x) | ((unsigned)f2bf(v.y) << 16);
      const unsigned int hi = (unsigned)f2bf(v.z) | ((unsigned)f2bf(v.w) << 16);
      *reinterpret_cast<uint2*>(&xl[cl][nq * 4]) = make_uint2(lo, hi);
    }
    __syncthreads();
    // B fragment: lane holds col n = wv*16+col, k(c) = kc*32 + grp*8 .. +7
    s16x8 bfrag;
#pragma unroll
    for (int j = 0; j < 8; ++j)
      bfrag[j] = (short)xl[grp * 8 + j][wv * 16 + col];
#pragma unroll
    for (int r = 0; r < 12; ++r) {
      // A fragment: contiguous 1KB wave-load from wcat2
      const s16x8 af = *reinterpret_cast<const s16x8*>(
          wcat2 + (size_t)(r * 8 + kc) * 512 + l * 8);
      acc[r] = __builtin_amdgcn_mfma_f32_16x16x32_bf16(af, bfrag, acc[r], 0, 0, 0);
    }
    __syncthreads();  // protect xl before next chunk's writes
  }
#pragma unroll
  for (int r = 0; r < 12; ++r)
#pragma unroll
    for (int q = 0; q < 4; ++q)
      ol[r * 16 + grp * 4 + q][wv * 16 + col] = f2bf(acc[r][q]);
  __syncthreads();
  unsigned short* thb = theta + (size_t)b * NN * CA;
  for (int i = tid; i < 128 * 16; i += 512) {
    const int n = i >> 4, cp = (i & 15) << 1;
    const unsigned int v = (unsigned)ol[cp][n] | ((unsigned)ol[cp + 1][n] << 16);
    *reinterpret_cast<unsigned int*>(thb + (size_t)(t * 128 + n) * CA + cp) = v;
  }
  unsigned short* phb2 = phi2 + (size_t)b * MM * CA;
  for (int i = tid; i < 32 * 32; i += 512) {
    const int ca = i & 31, mx = i >> 5;
    const float v = fmaxf(
        fmaxf(bf2f(ol[32 + ca][2 * mx]), bf2f(ol[32 + ca][2 * mx + 1])),
        fmaxf(bf2f(ol[32 + ca][64 + 2 * mx]), bf2f(ol[32 + ca][64 + 2 * mx + 1])));
    const int m = t * 32 + mx;
    phb2[(m >> 4) * 512 + (ca >> 3) * 128 + (m & 15) * 8 + (ca & 7)] = f2bf(v);
  }
  unsigned short* gb2 = g2 + (size_t)b * CH * MM;
  for (int i = tid; i < 128 * 32; i += 512) {
    const int mx = i & 31, c = i >> 5;
    const float v = fmaxf(
        fmaxf(bf2f(ol[64 + c][2 * mx]), bf2f(ol[64 + c][2 * mx + 1])),
        fmaxf(bf2f(ol[64 + c][64 + 2 * mx]), bf2f(ol[64 + c][64 + 2 * mx + 1])));
    gb2[(size_t)(t * 8 + (c >> 4)) * 512 + ((mx >> 3) & 3) * 128 + (c & 15) * 8 +
        (mx & 7)] = f2bf(v);
  }
}

// Flash attention v3.1: 4 waves x 32 n-cols; LDS-staged K/V double-buffered via
// global_load_lds; single-nt pl buffer reused sequentially.
__global__ __launch_bounds__(256, 3) void k_attn_out(
    const unsigned short* __restrict__ theta, const unsigned short* __restrict__ phi2,
    const unsigned short* __restrict__ g2, const unsigned short* __restrict__ wo2,
    const float* __restrict__ x, const float* __restrict__ gammap,
    float* __restrict__ out) {
  __shared__ __align__(16) unsigned short kv[2][10240];   // [buf][K 2048 | V 8192]
  __shared__ __align__(16) unsigned short pl[4][16][72];  // per-wave, reused per nt
  const int b = blockIdx.y;
  const int tid = threadIdx.x;
  const int wv = tid >> 6;
  const int l = tid & 63;
  const int grp = l >> 4, col = l & 15;
  const int n0 = blockIdx.x * 128 + wv * 32;
  const unsigned short* thb = theta + (size_t)b * NN * CA;
  const unsigned short* ph2b = phi2 + (size_t)b * MM * CA;
  const unsigned short* gb2 = g2 + (size_t)b * CH * MM;
  const s16x8 qf0 = *reinterpret_cast<const s16x8*>(thb + (size_t)(n0 + col) * CA + grp * 8);
  const s16x8 qf1 = *reinterpret_cast<const s16x8*>(thb + (size_t)(n0 + 16 + col) * CA + grp * 8);

  auto STAGE = [&](int buf, int tile) {
    const int mc = tile * 64;
    const unsigned short* ksrc = ph2b + (mc >> 4) * 512;
    const unsigned short* vsrc = gb2 + (size_t)(mc >> 5) * 4096;
#pragma unroll
    for (int q = 0; q < 5; ++q) {
      const int i = wv * 5 + q;
      const unsigned short* src = (i < 4) ? (ksrc + i * 512) : (vsrc + (i - 4) * 512);
      gload_lds16(src + (size_t)l * 8, &kv[buf][i * 512]);
    }
  };

  f32x4 oa0[8], oa1[8];
#pragma unroll
  for (int t = 0; t < 8; ++t) {
    oa0[t] = f32x4{0.f, 0.f, 0.f, 0.f};
    oa1[t] = f32x4{0.f, 0.f, 0.f, 0.f};
  }
  float m0 = -INFINITY, l0 = 0.f, m1 = -INFINITY, l1 = 0.f;
  const f32x4 z4 = {0.f, 0.f, 0.f, 0.f};

  STAGE(0, 0);
  __syncthreads();
#pragma unroll 1
  for (int it = 0; it < 16; ++it) {
    const int cur = it & 1;
    if (it < 15) STAGE(cur ^ 1, it + 1);  // fire-and-forget DMA for next tile
    const unsigned short* kb = &kv[cur][0];
    const unsigned short* vb = &kv[cur][2048];
    const int fo = grp * 128 + col * 8;
    const s16x8 kf0 = *reinterpret_cast<const s16x8*>(kb + 0 * 512 + fo);
    const s16x8 kf1 = *reinterpret_cast<const s16x8*>(kb + 1 * 512 + fo);
    const s16x8 kf2 = *reinterpret_cast<const s16x8*>(kb + 2 * 512 + fo);
    const s16x8 kf3 = *reinterpret_cast<const s16x8*>(kb + 3 * 512 + fo);
    f32x4 s00 = __builtin_amdgcn_mfma_f32_16x16x32_bf16(kf0, qf0, z4, 0, 0, 0);
    f32x4 s01 = __builtin_amdgcn_mfma_f32_16x16x32_bf16(kf1, qf0, z4, 0, 0, 0);
    f32x4 s02 = __builtin_amdgcn_mfma_f32_16x16x32_bf16(kf2, qf0, z4, 0, 0, 0);
    f32x4 s03 = __builtin_amdgcn_mfma_f32_16x16x32_bf16(kf3, qf0, z4, 0, 0, 0);
    f32x4 s10 = __builtin_amdgcn_mfma_f32_16x16x32_bf16(kf0, qf1, z4, 0, 0, 0);
    f32x4 s11 = __builtin_amdgcn_mfma_f32_16x16x32_bf16(kf1, qf1, z4, 0, 0, 0);
    f32x4 s12 = __builtin_amdgcn_mfma_f32_16x16x32_bf16(kf2, qf1, z4, 0, 0, 0);
    f32x4 s13 = __builtin_amdgcn_mfma_f32_16x16x32_bf16(kf3, qf1, z4, 0, 0, 0);
    float cm0 = -INFINITY, cm1 = -INFINITY;
#pragma unroll
    for (int r = 0; r < 4; ++r) {
      cm0 = fmaxf(cm0, fmaxf(fmaxf(s00[r], s01[r]), fmaxf(s02[r], s03[r])));
      cm1 = fmaxf(cm1, fmaxf(fmaxf(s10[r], s11[r]), fmaxf(s12[r], s13[r])));
    }
    cm0 = fmaxf(cm0, __shfl_xor(cm0, 16));
    cm0 = fmaxf(cm0, __shfl_xor(cm0, 32));
    cm1 = fmaxf(cm1, __shfl_xor(cm1, 16));
    cm1 = fmaxf(cm1, __shfl_xor(cm1, 32));
    if (!__all(cm0 <= m0 + 8.f && cm1 <= m1 + 8.f)) {  // defer-max (T13)
      const float mn0 = fmaxf(m0, cm0), mn1 = fmaxf(m1, cm1);
      const float sc0 = __expf(m0 - mn0), sc1 = __expf(m1 - mn1);
      l0 *= sc0;
      l1 *= sc1;
#pragma unroll
      for (int t = 0; t < 8; ++t) {
#pragma unroll
        for (int r = 0; r < 4; ++r) {
          oa0[t][r] *= sc0;
          oa1[t][r] *= sc1;
        }
      }
      m0 = mn0;
      m1 = mn1;
    }
    s16x8 pfA0, pfB0, pfA1, pfB1;
    {  // nt0 softmax -> pl -> pf0 fragments
      float p0[4], p1[4], p2[4], p3[4];
      float cs = 0.f;
#pragma unroll
      for (int r = 0; r < 4; ++r) {
        p0[r] = __expf(s00[r] - m0);
        p1[r] = __expf(s01[r] - m0);
        p2[r] = __expf(s02[r] - m0);
        p3[r] = __expf(s03[r] - m0);
        cs += (p0[r] + p1[r]) + (p2[r] + p3[r]);
      }
      cs += __shfl_xor(cs, 16);
      cs += __shfl_xor(cs, 32);
      l0 += cs;
      *reinterpret_cast<uint2*>(&pl[wv][col][grp * 4]) =
          make_uint2((unsigned)f2bf(p0[0]) | ((unsigned)f2bf(p0[1]) << 16),
                     (unsigned)f2bf(p0[2]) | ((unsigned)f2bf(p0[3]) << 16));
      *reinterpret_cast<uint2*>(&pl[wv][col][16 + grp * 4]) =
          make_uint2((unsigned)f2bf(p1[0]) | ((unsigned)f2bf(p1[1]) << 16),
                     (unsigned)f2bf(p1[2]) | ((unsigned)f2bf(p1[3]) << 16));
      *reinterpret_cast<uint2*>(&pl[wv][col][32 + grp * 4]) =
          make_uint2((unsigned)f2bf(p2[0]) | ((unsigned)f2bf(p2[1]) << 16),
                     (unsigned)f2bf(p2[2]) | ((unsigned)f2bf(p2[3]) << 16));
      *reinterpret_cast<uint2*>(&pl[wv][col][48 + grp * 4]) =
          make_uint2((unsigned)f2bf(p3[0]) | ((unsigned)f2bf(p3[1]) << 16),
                     (unsigned)f2bf(p3[2]) | ((unsigned)f2bf(p3[3]) << 16));
      pfA0 = *reinterpret_cast<const s16x8*>(&pl[wv][col][grp * 8]);
      pfB0 = *reinterpret_cast<const s16x8*>(&pl[wv][col][32 + grp * 8]);
    }
    {  // nt1 softmax -> pl (reuse) -> pf1 fragments
      float p0[4], p1[4], p2[4], p3[4];
      float cs = 0.f;
#pragma unroll
      for (int r = 0; r < 4; ++r) {
        p0[r] = __expf(s10[r] - m1);
        p1[r] = __expf(s11[r] - m1);
        p2[r] = __expf(s12[r] - m1);
        p3[r] = __expf(s13[r] - m1);
        cs += (p0[r] + p1[r]) + (p2[r] + p3[r]);
      }
      cs += __shfl_xor(cs, 16);
      cs += __shfl_xor(cs, 32);
      l1 += cs;
      *reinterpret_cast<uint2*>(&pl[wv][col][grp * 4]) =
          make_uint2((unsigned)f2bf(p0[0]) | ((unsigned)f2bf(p0[1]) << 16),
                     (unsigned)f2bf(p0[2]) | ((unsigned)f2bf(p0[3]) << 16));
      *reinterpret_cast<uint2*>(&pl[wv][col][16 + grp * 4]) =
          make_uint2((unsigned)f2bf(p1[0]) | ((unsigned)f2bf(p1[1]) << 16),
                     (unsigned)f2bf(p1[2]) | ((unsigned)f2bf(p1[3]) << 16));
      *reinterpret_cast<uint2*>(&pl[wv][col][32 + grp * 4]) =
          make_uint2((unsigned)f2bf(p2[0]) | ((unsigned)f2bf(p2[1]) << 16),
                     (unsigned)f2bf(p2[2]) | ((unsigned)f2bf(p2[3]) << 16));
      *reinterpret_cast<uint2*>(&pl[wv][col][48 + grp * 4]) =
          make_uint2((unsigned)f2bf(p3[0]) | ((unsigned)f2bf(p3[1]) << 16),
                     (unsigned)f2bf(p3[2]) | ((unsigned)f2bf(p3[3]) << 16));
      pfA1 = *reinterpret_cast<const s16x8*>(&pl[wv][col][grp * 8]);
      pfB1 = *reinterpret_cast<const s16x8*>(&pl[wv][col][32 + grp * 8]);
    }
#pragma unroll
    for (int t = 0; t < 8; ++t) {
      const s16x8 vfA = *reinterpret_cast<const s16x8*>(vb + t * 512 + fo);
      const s16x8 vfB = *reinterpret_cast<const s16x8*>(vb + 4096 + t * 512 + fo);
      oa0[t] = __builtin_amdgcn_mfma_f32_16x16x32_bf16(vfA, pfA0, oa0[t], 0, 0, 0);
      oa0[t] = __builtin_amdgcn_mfma_f32_16x16x32_bf16(vfB, pfB0, oa0[t], 0, 0, 0);
      oa1[t] = __builtin_amdgcn_mfma_f32_16x16x32_bf16(vfA, pfA1, oa1[t], 0, 0, 0);
      oa1[t] = __builtin_amdgcn_mfma_f32_16x16x32_bf16(vfB, pfB1, oa1[t], 0, 0, 0);
    }
    __syncthreads();
  }
  // ---- epilogue: normalize own O, stage in LDS (reuse kv), project ----
  unsigned short* obw = &kv[0][0] + (size_t)wv * (32 * 136);
  const float ri0 = 1.f / l0, ri1 = 1.f / l1;
#pragma unroll
  for (int t = 0; t < 8; ++t) {
    *reinterpret_cast<uint2*>(obw + col * 136 + t * 16 + grp * 4) =
        make_uint2((unsigned)f2bf(oa0[t][0] * ri0) | ((unsigned)f2bf(oa0[t][1] * ri0) << 16),
                   (unsigned)f2bf(oa0[t][2] * ri0) | ((unsigned)f2bf(oa0[t][3] * ri0) << 16));
    *reinterpret_cast<uint2*>(obw + (16 + col) * 136 + t * 16 + grp * 4) =
        make_uint2((unsigned)f2bf(oa1[t][0] * ri1) | ((unsigned)f2bf(oa1[t][1] * ri1) << 16),
                   (unsigned)f2bf(oa1[t][2] * ri1) | ((unsigned)f2bf(oa1[t][3] * ri1) << 16));
  }
  s16x8 of0[4], of1[4];
#pragma unroll
  for (int ks = 0; ks < 4; ++ks) {
    of0[ks] = *reinterpret_cast<const s16x8*>(obw + col * 136 + ks * 32 + grp * 8);
    of1[ks] = *reinterpret_cast<const s16x8*>(obw + (16 + col) * 136 + ks * 32 + grp * 8);
  }
  const float gamma = gammap[0];
  const float* xb2 = x + (size_t)b * CIN * NN;
  float* outb = out + (size_t)b * CIN * NN;
#pragma unroll 1
  for (int t2 = 0; t2 < 16; ++t2) {
    f32x4 a20 = {0.f, 0.f, 0.f, 0.f};
    f32x4 a21 = {0.f, 0.f, 0.f, 0.f};
#pragma unroll
    for (int ks = 0; ks < 4; ++ks) {
      const s16x8 wf = *reinterpret_cast<const s16x8*>(
          wo2 + (size_t)(t2 * 16 + ks * 4 + grp) * 128 + col * 8);
      a20 = __builtin_amdgcn_mfma_f32_16x16x32_bf16(wf, of0[ks], a20, 0, 0, 0);
      a21 = __builtin_amdgcn_mfma_f32_16x16x32_bf16(wf, of1[ks], a21, 0, 0, 0);
    }
#pragma unroll
    for (int r = 0; r < 4; ++r) {
      const size_t idx = (size_t)(t2 * 16 + grp * 4 + r) * NN + n0 + col;
      outb[idx] = fmaf(gamma, a20[r], xb2[idx]);
      outb[idx + 16] = fmaf(gamma, a21[r], xb2[idx + 16]);
    }
  }
}

extern "C" void kernel_launch(void* const* d_in, const int* in_sizes, int n_in,
                              void* d_out, int out_size, void* d_ws, size_t ws_size,
                              hipStream_t stream) {
  const float* x = (const float*)d_in[0];
  const float* w_theta = (const float*)d_in[1];
  const float* w_phi = (const float*)d_in[2];
  const float* w_g = (const float*)d_in[3];
  const float* w_o = (const float*)d_in[4];
  const float* gamma = (const float*)d_in[5];
  float* out = (float*)d_out;
  char* ws = (char*)d_ws;
  unsigned short* theta = (unsigned short*)(ws + 0);
  unsigned short* phi2 = (unsigned short*)(ws + 4194304);
  unsigned short* g2 = (unsigned short*)(ws + 5242880);
  unsigned short* wo2 = (unsigned short*)(ws + 9437184);
  unsigned short* wcat2 = (unsigned short*)(ws + 9502720);

  k_wcvt<<<dim3(320), 256, 0, stream>>>(w_theta, w_phi, w_g, w_o, wcat2, wo2);
  k_proj<<<dim3(NN / 128, NB), 512, 0, stream>>>(x, wcat2, theta, phi2, g2);
  k_attn_out<<<dim3(NN / 128, NB), 256, 0, stream>>>(theta, phi2, g2, wo2, x, gamma, out);
}

// Round 13
// 88.235 us; speedup vs baseline: 1.4467x; 1.0076x over previous
//
#include <hip/hip_runtime.h>
#include <hip/hip_bf16.h>

#define NB 16
#define CIN 256
#define CA 32
#define CH 128
#define NN 4096
#define MM 1024

typedef __attribute__((ext_vector_type(8))) short s16x8;
typedef __attribute__((ext_vector_type(4))) float f32x4;

static __device__ __forceinline__ unsigned short f2bf(float x) {
  __hip_bfloat16 h = __float2bfloat16(x);
  return __builtin_bit_cast(unsigned short, h);
}
static __device__ __forceinline__ float bf2f(unsigned short u) {
  unsigned int v = ((unsigned int)u) << 16;
  return __builtin_bit_cast(float, v);
}
// async global->LDS DMA, 16B per lane; lds dst is wave-uniform base + lane*16
static __device__ __forceinline__ void gload_lds16(const void* g, void* s) {
  __builtin_amdgcn_global_load_lds(
      (const __attribute__((address_space(1))) unsigned int*)g,
      (__attribute__((address_space(3))) unsigned int*)s, 16, 0, 0);
}

// Build wcat2 (A-fragment-packed [w_theta; w_phi; w_g]) and wo2 (fragment-packed).
__global__ __launch_bounds__(256) void k_wcvt(const float* __restrict__ w_theta,
                                              const float* __restrict__ w_phi,
                                              const float* __restrict__ w_g,
                                              const float* __restrict__ w_o,
                                              unsigned short* __restrict__ wcat2,
                                              unsigned short* __restrict__ wo2) {
  const int i = blockIdx.x * 256 + threadIdx.x;
  if (i < 49152) {
    const int row = i >> 8, c = i & 255;
    const float v = (row < 32) ? w_theta[i]
                  : (row < 64) ? w_phi[i - 8192]
                               : w_g[i - 16384];
    const int dst = ((row >> 4) * 8 + (c >> 5)) * 512 +
                    (((c >> 3) & 3) * 16 + (row & 15)) * 8 + (c & 7);
    wcat2[dst] = f2bf(v);
  } else {
    const int w = i - 49152;
    const int c_out = w >> 7, k = w & 127;
    const int dst = (((c_out >> 4) * 16) + ((k >> 5) * 4) + ((k >> 3) & 3)) * 128 +
                    ((c_out & 15) << 3) + (k & 7);
    wo2[dst] = f2bf(w_o[w]);
  }
}

// MFMA projection, fused in-LDS transpose of x, A-fragments contiguous from wcat2.
__global__ __launch_bounds__(512) void k_proj(const float* __restrict__ x,
                                              const unsigned short* __restrict__ wcat2,
                                              unsigned short* __restrict__ theta,
                                              unsigned short* __restrict__ phi2,
                                              unsigned short* __restrict__ g2) {
  __shared__ unsigned short xl[32][140];
  __shared__ unsigned short ol[192][136];
  const int b = blockIdx.y;
  const int t = blockIdx.x;
  const int tid = threadIdx.x;
  const int wv = tid >> 6;
  const int l = tid & 63;
  const int grp = l >> 4, col = l & 15;
  const float* xb = x + (size_t)b * CIN * NN;
  f32x4 acc[12];
#pragma unroll
  for (int r = 0; r < 12; ++r) acc[r] = f32x4{0.f, 0.f, 0.f, 0.f};
#pragma unroll 1
  for (int kc = 0; kc < 8; ++kc) {
#pragma unroll
    for (int s = 0; s < 2; ++s) {
      const int i = tid + s * 512;
      const int cl = i >> 5, nq = i & 31;
      const float4 v = *reinterpret_cast<const float4*>(
          xb + (size_t)(kc * 32 + cl) * NN + t * 128 + nq * 4);
      const unsigned int lo = (unsigned)f2bf(v.x) | ((unsigned)f2bf(v.y) << 16);
      const unsigned int hi = (unsigned)f2bf(v.z) | ((unsigned)f2bf(v.w) << 16);
      *reinterpret_cast<uint2*>(&xl[cl][nq * 4]) = make_uint2(lo, hi);
    }
    __syncthreads();
    s16x8 bfrag;
#pragma unroll
    for (int j = 0; j < 8; ++j)
      bfrag[j] = (short)xl[grp * 8 + j][wv * 16 + col];
#pragma unroll
    for (int r = 0; r < 12; ++r) {
      const s16x8 af = *reinterpret_cast<const s16x8*>(
          wcat2 + (size_t)(r * 8 + kc) * 512 + l * 8);
      acc[r] = __builtin_amdgcn_mfma_f32_16x16x32_bf16(af, bfrag, acc[r], 0, 0, 0);
    }
    __syncthreads();
  }
#pragma unroll
  for (int r = 0; r < 12; ++r)
#pragma unroll
    for (int q = 0; q < 4; ++q)
      ol[r * 16 + grp * 4 + q][wv * 16 + col] = f2bf(acc[r][q]);
  __syncthreads();
  unsigned short* thb = theta + (size_t)b * NN * CA;
  for (int i = tid; i < 128 * 16; i += 512) {
    const int n = i >> 4, cp = (i & 15) << 1;
    const unsigned int v = (unsigned)ol[cp][n] | ((unsigned)ol[cp + 1][n] << 16);
    *reinterpret_cast<unsigned int*>(thb + (size_t)(t * 128 + n) * CA + cp) = v;
  }
  unsigned short* phb2 = phi2 + (size_t)b * MM * CA;
  for (int i = tid; i < 32 * 32; i += 512) {
    const int ca = i & 31, mx = i >> 5;
    const float v = fmaxf(
        fmaxf(bf2f(ol[32 + ca][2 * mx]), bf2f(ol[32 + ca][2 * mx + 1])),
        fmaxf(bf2f(ol[32 + ca][64 + 2 * mx]), bf2f(ol[32 + ca][64 + 2 * mx + 1])));
    const int m = t * 32 + mx;
    phb2[(m >> 4) * 512 + (ca >> 3) * 128 + (m & 15) * 8 + (ca & 7)] = f2bf(v);
  }
  unsigned short* gb2 = g2 + (size_t)b * CH * MM;
  for (int i = tid; i < 128 * 32; i += 512) {
    const int mx = i & 31, c = i >> 5;
    const float v = fmaxf(
        fmaxf(bf2f(ol[64 + c][2 * mx]), bf2f(ol[64 + c][2 * mx + 1])),
        fmaxf(bf2f(ol[64 + c][64 + 2 * mx]), bf2f(ol[64 + c][64 + 2 * mx + 1])));
    gb2[(size_t)(t * 8 + (c >> 4)) * 512 + ((mx >> 3) & 3) * 128 + (c & 15) * 8 +
        (mx & 7)] = f2bf(v);
  }
}

// Flash attention v4: 8 waves, split-K in block. Waves 0-3: keys 0-511,
// waves 4-7: keys 512-1023; wave gw owns 32 n-cols. Per-group double-buffered
// 32-key K/V LDS tiles via DMA. LDS merge at end + split out-projection.
__global__ __launch_bounds__(512, 4) void k_attn_out(
    const unsigned short* __restrict__ theta, const unsigned short* __restrict__ phi2,
    const unsigned short* __restrict__ g2, const unsigned short* __restrict__ wo2,
    const float* __restrict__ x, const float* __restrict__ gammap,
    float* __restrict__ out) {
  __shared__ __align__(16) unsigned short kv[2][2][5120];  // [grpH][buf][K 1024 | V 4096]
  __shared__ __align__(16) unsigned short pl[8][16][40];   // per-wave P^T, reused per nt
  __shared__ float mlb[8][2][32];                          // [wave][{m,l}][nt*16+n]
  const int b = blockIdx.y;
  const int tid = threadIdx.x;
  const int wv = tid >> 6;
  const int h = wv >> 2;   // key-half group
  const int gw = wv & 3;   // wave-in-group: owns cols gw*32..+31
  const int l = tid & 63;
  const int grp = l >> 4, col = l & 15;
  const int n0 = blockIdx.x * 128 + gw * 32;
  const unsigned short* thb = theta + (size_t)b * NN * CA;
  const unsigned short* ph2b = phi2 + (size_t)b * MM * CA;
  const unsigned short* gb2 = g2 + (size_t)b * CH * MM;
  const s16x8 qf0 = *reinterpret_cast<const s16x8*>(thb + (size_t)(n0 + col) * CA + grp * 8);
  const s16x8 qf1 = *reinterpret_cast<const s16x8*>(thb + (size_t)(n0 + 16 + col) * CA + grp * 8);

  // stage 32-key tile for this wave's group: K 1024 shorts + V 4096 shorts = 10 DMAs,
  // split 3/3/2/2 across the group's 4 waves.
  auto STAGE = [&](int buf, int tile) {
    const int mc = h * 512 + tile * 32;
    const unsigned short* ksrc = ph2b + (mc >> 4) * 512;
    const unsigned short* vsrc = gb2 + (size_t)(mc >> 5) * 4096;
    unsigned short* dst = &kv[h][buf][0];
#pragma unroll
    for (int q = 0; q < 2; ++q) {
      const int i = gw + q * 4;
      const unsigned short* src = (i < 2) ? (ksrc + i * 512) : (vsrc + (size_t)(i - 2) * 512);
      gload_lds16(src + (size_t)l * 8, dst + i * 512);
    }
    if (gw < 2) {
      const int i = gw + 8;
      gload_lds16(vsrc + (size_t)(i - 2) * 512 + (size_t)l * 8, dst + i * 512);
    }
  };

  f32x4 oa0[8], oa1[8];
#pragma unroll
  for (int t = 0; t < 8; ++t) {
    oa0[t] = f32x4{0.f, 0.f, 0.f, 0.f};
    oa1[t] = f32x4{0.f, 0.f, 0.f, 0.f};
  }
  float m0 = -INFINITY, l0 = 0.f, m1 = -INFINITY, l1 = 0.f;
  const f32x4 z4 = {0.f, 0.f, 0.f, 0.f};

  STAGE(0, 0);
  __syncthreads();
#pragma unroll 1
  for (int it = 0; it < 16; ++it) {
    const int cur = it & 1;
    if (it < 15) STAGE(cur ^ 1, it + 1);  // fire-and-forget DMA for next tile
    const unsigned short* kb = &kv[h][cur][0];
    const unsigned short* vb = kb + 1024;
    const int fo = grp * 128 + col * 8;
    const s16x8 kf0 = *reinterpret_cast<const s16x8*>(kb + fo);
    const s16x8 kf1 = *reinterpret_cast<const s16x8*>(kb + 512 + fo);
    f32x4 s00 = __builtin_amdgcn_mfma_f32_16x16x32_bf16(kf0, qf0, z4, 0, 0, 0);
    f32x4 s01 = __builtin_amdgcn_mfma_f32_16x16x32_bf16(kf1, qf0, z4, 0, 0, 0);
    f32x4 s10 = __builtin_amdgcn_mfma_f32_16x16x32_bf16(kf0, qf1, z4, 0, 0, 0);
    f32x4 s11 = __builtin_amdgcn_mfma_f32_16x16x32_bf16(kf1, qf1, z4, 0, 0, 0);
    float cm0 = -INFINITY, cm1 = -INFINITY;
#pragma unroll
    for (int r = 0; r < 4; ++r) {
      cm0 = fmaxf(cm0, fmaxf(s00[r], s01[r]));
      cm1 = fmaxf(cm1, fmaxf(s10[r], s11[r]));
    }
    cm0 = fmaxf(cm0, __shfl_xor(cm0, 16));
    cm0 = fmaxf(cm0, __shfl_xor(cm0, 32));
    cm1 = fmaxf(cm1, __shfl_xor(cm1, 16));
    cm1 = fmaxf(cm1, __shfl_xor(cm1, 32));
    if (!__all(cm0 <= m0 + 8.f && cm1 <= m1 + 8.f)) {  // defer-max (T13)
      const float mn0 = fmaxf(m0, cm0), mn1 = fmaxf(m1, cm1);
      const float sc0 = __expf(m0 - mn0), sc1 = __expf(m1 - mn1);
      l0 *= sc0;
      l1 *= sc1;
#pragma unroll
      for (int t = 0; t < 8; ++t) {
#pragma unroll
        for (int r = 0; r < 4; ++r) {
          oa0[t][r] *= sc0;
          oa1[t][r] *= sc1;
        }
      }
      m0 = mn0;
      m1 = mn1;
    }
    s16x8 pfA0, pfA1;
    {  // nt0 softmax -> pl -> fragment
      float p0[4], p1[4];
      float cs = 0.f;
#pragma unroll
      for (int r = 0; r < 4; ++r) {
        p0[r] = __expf(s00[r] - m0);
        p1[r] = __expf(s01[r] - m0);
        cs += p0[r] + p1[r];
      }
      cs += __shfl_xor(cs, 16);
      cs += __shfl_xor(cs, 32);
      l0 += cs;
      *reinterpret_cast<uint2*>(&pl[wv][col][grp * 4]) =
          make_uint2((unsigned)f2bf(p0[0]) | ((unsigned)f2bf(p0[1]) << 16),
                     (unsigned)f2bf(p0[2]) | ((unsigned)f2bf(p0[3]) << 16));
      *reinterpret_cast<uint2*>(&pl[wv][col][16 + grp * 4]) =
          make_uint2((unsigned)f2bf(p1[0]) | ((unsigned)f2bf(p1[1]) << 16),
                     (unsigned)f2bf(p1[2]) | ((unsigned)f2bf(p1[3]) << 16));
      pfA0 = *reinterpret_cast<const s16x8*>(&pl[wv][col][grp * 8]);
    }
    {  // nt1 softmax -> pl (sequential reuse) -> fragment
      float p0[4], p1[4];
      float cs = 0.f;
#pragma unroll
      for (int r = 0; r < 4; ++r) {
        p0[r] = __expf(s10[r] - m1);
        p1[r] = __expf(s11[r] - m1);
        cs += p0[r] + p1[r];
      }
      cs += __shfl_xor(cs, 16);
      cs += __shfl_xor(cs, 32);
      l1 += cs;
      *reinterpret_cast<uint2*>(&pl[wv][col][grp * 4]) =
          make_uint2((unsigned)f2bf(p0[0]) | ((unsigned)f2bf(p0[1]) << 16),
                     (unsigned)f2bf(p0[2]) | ((unsigned)f2bf(p0[3]) << 16));
      *reinterpret_cast<uint2*>(&pl[wv][col][16 + grp * 4]) =
          make_uint2((unsigned)f2bf(p1[0]) | ((unsigned)f2bf(p1[1]) << 16),
                     (unsigned)f2bf(p1[2]) | ((unsigned)f2bf(p1[3]) << 16));
      pfA1 = *reinterpret_cast<const s16x8*>(&pl[wv][col][grp * 8]);
    }
#pragma unroll
    for (int t = 0; t < 8; ++t) {
      const s16x8 vfA = *reinterpret_cast<const s16x8*>(vb + t * 512 + fo);
      oa0[t] = __builtin_amdgcn_mfma_f32_16x16x32_bf16(vfA, pfA0, oa0[t], 0, 0, 0);
      oa1[t] = __builtin_amdgcn_mfma_f32_16x16x32_bf16(vfA, pfA1, oa1[t], 0, 0, 0);
    }
    __syncthreads();  // drains DMA + buffer swap (both groups)
  }
  // ---- split-K merge across wave pair (wv, wv^4) ----
  if (grp == 0) {
    mlb[wv][0][col] = m0;
    mlb[wv][1][col] = l0;
    mlb[wv][0][16 + col] = m1;
    mlb[wv][1][16 + col] = l1;
  }
  __syncthreads();
  const int pw = wv ^ 4;
  const float mo0 = mlb[pw][0][col], lo0 = mlb[pw][1][col];
  const float mo1 = mlb[pw][0][16 + col], lo1 = mlb[pw][1][16 + col];
  const float mt0 = fmaxf(m0, mo0), mt1 = fmaxf(m1, mo1);
  const float sc0 = __expf(m0 - mt0), sc1 = __expf(m1 - mt1);
  const float lt0 = l0 * sc0 + lo0 * __expf(mo0 - mt0);
  const float lt1 = l1 * sc1 + lo1 * __expf(mo1 - mt1);
  unsigned short* mb = &kv[0][0][0] + (size_t)gw * (32 * 136);
  if (h == 1) {  // stage scaled O for both n-tiles
#pragma unroll
    for (int t = 0; t < 8; ++t) {
      *reinterpret_cast<uint2*>(mb + col * 136 + t * 16 + grp * 4) =
          make_uint2((unsigned)f2bf(oa0[t][0] * sc0) | ((unsigned)f2bf(oa0[t][1] * sc0) << 16),
                     (unsigned)f2bf(oa0[t][2] * sc0) | ((unsigned)f2bf(oa0[t][3] * sc0) << 16));
      *reinterpret_cast<uint2*>(mb + (16 + col) * 136 + t * 16 + grp * 4) =
          make_uint2((unsigned)f2bf(oa1[t][0] * sc1) | ((unsigned)f2bf(oa1[t][1] * sc1) << 16),
                     (unsigned)f2bf(oa1[t][2] * sc1) | ((unsigned)f2bf(oa1[t][3] * sc1) << 16));
    }
  }
  __syncthreads();
  if (h == 0) {  // merge + normalize
    const float ri0 = 1.f / lt0, ri1 = 1.f / lt1;
#pragma unroll
    for (int t = 0; t < 8; ++t) {
      float v0[4], v1[4];
#pragma unroll
      for (int q = 0; q < 4; ++q) {
        v0[q] = (oa0[t][q] * sc0 + bf2f(mb[col * 136 + t * 16 + grp * 4 + q])) * ri0;
        v1[q] = (oa1[t][q] * sc1 + bf2f(mb[(16 + col) * 136 + t * 16 + grp * 4 + q])) * ri1;
      }
      *reinterpret_cast<uint2*>(mb + col * 136 + t * 16 + grp * 4) =
          make_uint2((unsigned)f2bf(v0[0]) | ((unsigned)f2bf(v0[1]) << 16),
                     (unsigned)f2bf(v0[2]) | ((unsigned)f2bf(v0[3]) << 16));
      *reinterpret_cast<uint2*>(mb + (16 + col) * 136 + t * 16 + grp * 4) =
          make_uint2((unsigned)f2bf(v1[0]) | ((unsigned)f2bf(v1[1]) << 16),
                     (unsigned)f2bf(v1[2]) | ((unsigned)f2bf(v1[3]) << 16));
    }
  }
  __syncthreads();
  // ---- fused out-projection: pair splits 16 row-tiles 8/8, wf shared ----
  s16x8 of0[4], of1[4];
#pragma unroll
  for (int ks = 0; ks < 4; ++ks) {
    of0[ks] = *reinterpret_cast<const s16x8*>(mb + col * 136 + ks * 32 + grp * 8);
    of1[ks] = *reinterpret_cast<const s16x8*>(mb + (16 + col) * 136 + ks * 32 + grp * 8);
  }
  const float gamma = gammap[0];
  const float* xb2 = x + (size_t)b * CIN * NN;
  float* outb = out + (size_t)b * CIN * NN;
  const int t2base = h * 8;
#pragma unroll 1
  for (int t2i = 0; t2i < 8; ++t2i) {
    const int t2 = t2base + t2i;
    f32x4 a20 = {0.f, 0.f, 0.f, 0.f};
    f32x4 a21 = {0.f, 0.f, 0.f, 0.f};
#pragma unroll
    for (int ks = 0; ks < 4; ++ks) {
      const s16x8 wf = *reinterpret_cast<const s16x8*>(
          wo2 + (size_t)(t2 * 16 + ks * 4 + grp) * 128 + col * 8);
      a20 = __builtin_amdgcn_mfma_f32_16x16x32_bf16(wf, of0[ks], a20, 0, 0, 0);
      a21 = __builtin_amdgcn_mfma_f32_16x16x32_bf16(wf, of1[ks], a21, 0, 0, 0);
    }
#pragma unroll
    for (int r = 0; r < 4; ++r) {
      const size_t idx = (size_t)(t2 * 16 + grp * 4 + r) * NN + n0 + col;
      outb[idx] = fmaf(gamma, a20[r], xb2[idx]);
      outb[idx + 16] = fmaf(gamma, a21[r], xb2[idx + 16]);
    }
  }
}

extern "C" void kernel_launch(void* const* d_in, const int* in_sizes, int n_in,
                              void* d_out, int out_size, void* d_ws, size_t ws_size,
                              hipStream_t stream) {
  const float* x = (const float*)d_in[0];
  const float* w_theta = (const float*)d_in[1];
  const float* w_phi = (const float*)d_in[2];
  const float* w_g = (const float*)d_in[3];
  const float* w_o = (const float*)d_in[4];
  const float* gamma = (const float*)d_in[5];
  float* out = (float*)d_out;
  char* ws = (char*)d_ws;
  unsigned short* theta = (unsigned short*)(ws + 0);
  unsigned short* phi2 = (unsigned short*)(ws + 4194304);
  unsigned short* g2 = (unsigned short*)(ws + 5242880);
  unsigned short* wo2 = (unsigned short*)(ws + 9437184);
  unsigned short* wcat2 = (unsigned short*)(ws + 9502720);

  k_wcvt<<<dim3(320), 256, 0, stream>>>(w_theta, w_phi, w_g, w_o, wcat2, wo2);
  k_proj<<<dim3(NN / 128, NB), 512, 0, stream>>>(x, wcat2, theta, phi2, g2);
  k_attn_out<<<dim3(NN / 128, NB), 512, 0, stream>>>(theta, phi2, g2, wo2, x, gamma, out);
}